// Round 14
// baseline (67.165 us; speedup 1.0000x reference)
//
#include <hip/hip_runtime.h>
#include <math.h>

#define DIM 128
#define BATCH 2048
#define NPREV 65536
#define NCH 64          // column chunks (1024 cols each)
#define DELTA 0.8f

typedef __attribute__((ext_vector_type(8))) short bf16x8;
typedef __attribute__((ext_vector_type(4))) float f32x4;
typedef unsigned short u16;

static __device__ __forceinline__ unsigned short f2bf(float f) {
    unsigned int u = __float_as_uint(f);
    u += 0x7FFF + ((u >> 16) & 1);          // RTNE
    return (unsigned short)(u >> 16);
}

// ---------- fused conv: B fragments + fused prev2 partials, and A fragments ----------
// B fragment (chunk,jt,s,fn): 64 lanes x 16B; lane l holds B[col = chunk*1024+jt*64+fn*16+(l&15)]
//   [k = (s>>1)*64 + (s&1)*32 + (l>>4)*8 .. +8].  Linear: frag*512u16 + lane*8.
//   frag = chunk*256 + jt*16 + s*4 + fn.
// p2part[srow*4+s] = sum over that 32-k block (shuffle-reduced over lhi: coalesced, 1MB).
// A fragment (strip,s,fm): 32-row strips; frag = strip*8 + s*2 + fm;
//   lane l holds A[row=strip*32+fm*16+(l&15)], same k mapping.
__global__ __launch_bounds__(256) void k_conv(const float* __restrict__ prevSrc,
                                              const float* __restrict__ tgSrc,
                                              u16* __restrict__ Bdst,
                                              u16* __restrict__ Adst,
                                              float* __restrict__ p2part) {
    const int b = blockIdx.x;
    if (b < 4096) {
        int id = b * 256 + threadIdx.x;           // 16384 frags * 64 lanes
        int lane = id & 63, frag = id >> 6;
        int fn = frag & 3, s = (frag >> 2) & 3, jt = (frag >> 4) & 15, chunk = frag >> 8;
        int srow = chunk * 1024 + jt * 64 + fn * 16 + (lane & 15);
        int scol = (s >> 1) * 64 + (s & 1) * 32 + (lane >> 4) * 8;
        const float* sp = prevSrc + (size_t)srow * DIM + scol;
        float4 f0 = *reinterpret_cast<const float4*>(sp);
        float4 f1 = *reinterpret_cast<const float4*>(sp + 4);
        float f[8] = {f0.x, f0.y, f0.z, f0.w, f1.x, f1.y, f1.z, f1.w};
        union { unsigned short us[8]; uint4 v; } o;
        float sum = 0.f;
        #pragma unroll
        for (int e = 0; e < 8; ++e) { o.us[e] = f2bf(f[e]); sum += f[e] * f[e]; }
        *reinterpret_cast<uint4*>(Bdst + (size_t)id * 8) = o.v;
        sum += __shfl_xor(sum, 16);
        sum += __shfl_xor(sum, 32);
        if ((lane >> 4) == 0) p2part[srow * 4 + s] = sum;   // coalesced-ish, 1 MB total
    } else {
        int id = (b - 4096) * 256 + threadIdx.x;  // 512 frags * 64 lanes
        int lane = id & 63, frag = id >> 6;
        int fm = frag & 1, s = (frag >> 1) & 3, strip = frag >> 3;   // 64 strips of 32 rows
        int srow = strip * 32 + fm * 16 + (lane & 15);
        int scol = (s >> 1) * 64 + (s & 1) * 32 + (lane >> 4) * 8;
        const float* sp = tgSrc + (size_t)srow * DIM + scol;
        float4 f0 = *reinterpret_cast<const float4*>(sp);
        float4 f1 = *reinterpret_cast<const float4*>(sp + 4);
        float f[8] = {f0.x, f0.y, f0.z, f0.w, f1.x, f1.y, f1.z, f1.w};
        union { unsigned short us[8]; uint4 v; } o;
        #pragma unroll
        for (int e = 0; e < 8; ++e) o.us[e] = f2bf(f[e]);
        *reinterpret_cast<uint4*>(Adst + (size_t)id * 8) = o.v;
    }
}

// ---------- prev2 reduce: p2h[j] = -0.5 * ||prev_j||^2 (deterministic fixed order) ----------
__global__ __launch_bounds__(256) void k_prev2r(const float* __restrict__ p2part,
                                                float* __restrict__ p2h) {
    int row = blockIdx.x * 256 + threadIdx.x;
    const float4 a = *reinterpret_cast<const float4*>(p2part + (size_t)row * 4);
    p2h[row] = -0.5f * ((a.x + a.y) + (a.z + a.w));
}

// ---------- main: barrier-free, LDS-free all-register GEMM screen ----------
// grid = 1024 blocks x 256 thr = 4096 waves (4/SIMD supplied; ~120 unified regs -> resident).
// Wave = 32 rows (strip) x 1024 cols (chunk). B streamed global->VGPR, double-banked.
// Screen s = dot - prev2/2 (maximize). Key stamp: [0:3]=l15 [4:7]=jt; fn group-coded (4).
__global__ __launch_bounds__(256, 2) void k_gemm_argmin(
    const u16* __restrict__ Aimg, const u16* __restrict__ Bimg,
    const float* __restrict__ p2h, float4* __restrict__ partial)
{
    const int t = threadIdx.x;
    const int lane = t & 63;
    const int w = t >> 6;
    const int l15 = lane & 15;
    const int lhi = lane >> 4;

    const int bid = blockIdx.x;
    const int chunk = bid & 63;          // bid%8 == chunk%8 -> XCD-local B stream
    const int strip = (bid >> 6) * 4 + w;   // 0..63 (32-row strips)

    // A fragments (32 VGPR), persistent
    bf16x8 areg[4][2];
    {
        const u16* ab = Aimg + ((size_t)strip * 8) * 512 + (size_t)lane * 8;
        #pragma unroll
        for (int s = 0; s < 4; ++s)
            #pragma unroll
            for (int fm = 0; fm < 2; ++fm)
                areg[s][fm] = *reinterpret_cast<const bf16x8*>(ab + (s * 2 + fm) * 512);
    }

    const u16* gb = Bimg + ((size_t)chunk * 256) * 512 + (size_t)lane * 8;
    const int phbase = chunk * 1024 + l15;
    const f32x4 z4 = {0.f, 0.f, 0.f, 0.f};

    float v1[2][4], v2[2][4];
    #pragma unroll
    for (int fm = 0; fm < 2; ++fm)
        #pragma unroll
        for (int r = 0; r < 4; ++r) { v1[fm][r] = -INFINITY; v2[fm][r] = -INFINITY; }

    f32x4 acc[2][4];
    bf16x8 bk0[4], bk1[4];

    // prologue: load stage 0 into bank0
    #pragma unroll
    for (int fn = 0; fn < 4; ++fn)
        bk0[fn] = *reinterpret_cast<const bf16x8*>(gb + fn * 512);

#define LOADBANK(BK, G) { \
        const u16* gp_ = gb + (size_t)(G) * 2048; \
        BK[0] = *reinterpret_cast<const bf16x8*>(gp_); \
        BK[1] = *reinterpret_cast<const bf16x8*>(gp_ + 512); \
        BK[2] = *reinterpret_cast<const bf16x8*>(gp_ + 1024); \
        BK[3] = *reinterpret_cast<const bf16x8*>(gp_ + 1536); }

#define MFMA_STAGE_INIT(BK, S) \
        _Pragma("unroll") \
        for (int fm = 0; fm < 2; ++fm) \
            _Pragma("unroll") \
            for (int fn = 0; fn < 4; ++fn) \
                acc[fm][fn] = __builtin_amdgcn_mfma_f32_16x16x32_bf16(areg[S][fm], BK[fn], z4, 0, 0, 0);

#define MFMA_STAGE_ACC(BK, S) \
        _Pragma("unroll") \
        for (int fm = 0; fm < 2; ++fm) \
            _Pragma("unroll") \
            for (int fn = 0; fn < 4; ++fn) \
                acc[fm][fn] = __builtin_amdgcn_mfma_f32_16x16x32_bf16(areg[S][fm], BK[fn], acc[fm][fn], 0, 0, 0);

    for (int jt = 0; jt < 16; ++jt) {
        const int g0 = jt * 4;
        float ph[4];
        #pragma unroll
        for (int fn = 0; fn < 4; ++fn) ph[fn] = p2h[phbase + jt * 64 + fn * 16];

        // s=0: prefetch s=1 into bk1, compute bk0
        LOADBANK(bk1, g0 + 1);
        __builtin_amdgcn_s_setprio(1);
        MFMA_STAGE_INIT(bk0, 0);
        __builtin_amdgcn_s_setprio(0);
        // s=1: prefetch s=2 into bk0, compute bk1
        LOADBANK(bk0, g0 + 2);
        __builtin_amdgcn_s_setprio(1);
        MFMA_STAGE_ACC(bk1, 1);
        __builtin_amdgcn_s_setprio(0);
        // s=2: prefetch s=3 into bk1, compute bk0
        LOADBANK(bk1, g0 + 3);
        __builtin_amdgcn_s_setprio(1);
        MFMA_STAGE_ACC(bk0, 2);
        __builtin_amdgcn_s_setprio(0);
        // s=3: prefetch next jt's s=0 into bk0, compute bk1
        if (jt + 1 < 16) LOADBANK(bk0, g0 + 4);
        __builtin_amdgcn_s_setprio(1);
        MFMA_STAGE_ACC(bk1, 3);
        __builtin_amdgcn_s_setprio(0);

        // epilogue: screen = dot + (-prev2/2); 4-fn max tree, stamped key, top-2
        const unsigned stamp = (unsigned)l15 | ((unsigned)jt << 4);
        #pragma unroll
        for (int fm = 0; fm < 2; ++fm) {
            #pragma unroll
            for (int r = 0; r < 4; ++r) {
                float s0 = acc[fm][0][r] + ph[0];
                float s1 = acc[fm][1][r] + ph[1];
                float s2 = acc[fm][2][r] + ph[2];
                float s3 = acc[fm][3][r] + ph[3];
                float m = fmaxf(fmaxf(s0, s1), fmaxf(s2, s3));
                float key = __uint_as_float((__float_as_uint(m) & ~0x7FFu) | stamp);
                float tm = fminf(v1[fm][r], key);
                v1[fm][r] = fmaxf(v1[fm][r], key);
                v2[fm][r] = fmaxf(v2[fm][r], tm);
            }
        }
    }
#undef LOADBANK
#undef MFMA_STAGE_INIT
#undef MFMA_STAGE_ACC

    // ---- butterfly top-2 merge over the 16 cols (l15) per row; write partial ----
    #pragma unroll
    for (int fm = 0; fm < 2; ++fm) {
        #pragma unroll
        for (int r = 0; r < 4; ++r) {
            float a1 = v1[fm][r], a2 = v2[fm][r];
            #pragma unroll
            for (int m = 1; m < 16; m <<= 1) {
                float o1 = __shfl_xor(a1, m), o2 = __shfl_xor(a2, m);
                float n2 = fmaxf(fminf(a1, o1), fmaxf(a2, o2));
                a1 = fmaxf(a1, o1); a2 = n2;
            }
            if (l15 == 0) {
                unsigned ua = __float_as_uint(a1), ub = __float_as_uint(a2);
                int row = strip * 32 + fm * 16 + lhi * 4 + r;
                int ja = chunk * 1024 + (int)((ua >> 4) & 15) * 64 + (int)(ua & 15);
                int jb = chunk * 1024 + (int)((ub >> 4) & 15) * 64 + (int)(ub & 15);
                partial[(size_t)row * NCH + chunk] = make_float4(
                    -2.0f * __uint_as_float(ua & ~0x7FFu), __int_as_float(ja),
                    -2.0f * __uint_as_float(ub & ~0x7FFu), __int_as_float(jb));
            }
        }
    }
}

// ---------- final: global reduce + exact fp32 recheck (4-col groups) + LP ----------
__global__ __launch_bounds__(256) void k_final2(
    const float* __restrict__ tg, const float* __restrict__ rg,
    const float* __restrict__ prev, const float4* __restrict__ partial,
    float* __restrict__ out_vals, float* __restrict__ out_grads)
{
    const int wv = threadIdx.x >> 6, lane = threadIdx.x & 63;
    const int i = blockIdx.x * 4 + wv;
    const float4 e = partial[(size_t)i * NCH + lane];   // 64 chunks x (top1, top2)

    float bv = e.x;
    #pragma unroll
    for (int m = 1; m < 64; m <<= 1) bv = fminf(bv, __shfl_xor(bv, m));

    unsigned long long m1 = __ballot(e.x <= bv + DELTA);
    unsigned long long m2 = __ballot(e.z <= bv + DELTA);
    const float2 g = *reinterpret_cast<const float2*>(tg + (size_t)i * DIM + 2 * lane);
    const int j1i = __float_as_int(e.y), j2i = __float_as_int(e.w);

    float bestd = INFINITY; int bestj = 0x7fffffff;
    while (m1 | m2) {
        int j0;
        if (m1) { int src = __ffsll(m1) - 1; m1 &= m1 - 1; j0 = __shfl(j1i, src); }
        else    { int src = __ffsll(m2) - 1; m2 &= m2 - 1; j0 = __shfl(j2i, src); }
        #pragma unroll
        for (int f = 0; f < 4; ++f) {
            int cj = j0 + f * 16;
            const float2 p = *reinterpret_cast<const float2*>(prev + (size_t)cj * DIM + 2 * lane);
            float dx = g.x - p.x, dy = g.y - p.y;
            float d = dx * dx + dy * dy;
            #pragma unroll
            for (int m = 1; m < 64; m <<= 1) d += __shfl_xor(d, m);
            if (d < bestd || (d == bestd && cj < bestj)) { bestd = d; bestj = cj; }
        }
    }

    const float2 s = *reinterpret_cast<const float2*>(prev + (size_t)bestj * DIM + 2 * lane);
    const float2 r = *reinterpret_cast<const float2*>(rg + (size_t)i * DIM + 2 * lane);
    const float dsx = g.x - s.x, dsy = g.y - s.y;
    const float drx = g.x - r.x, dry = g.y - r.y;
    float ds = dsx * dsx + dsy * dsy;
    float dr = drx * drx + dry * dry;
    #pragma unroll
    for (int m = 1; m < 64; m <<= 1) { ds += __shfl_xor(ds, m); dr += __shfl_xor(dr, m); }
    const float sds = sqrtf(ds), sdr = sqrtf(dr);
    if (lane == 0) out_vals[i] = sds - sdr;
    const float is = 1.0f / sds, ir = 1.0f / sdr;
    float2 gr;
    gr.x = dsx * is - drx * ir;
    gr.y = dsy * is - dry * ir;
    *reinterpret_cast<float2*>(out_grads + (size_t)i * DIM + 2 * lane) = gr;
}

// ================= fallback (round-1 verified fp32 path) =================
#define TM 128
#define TN 128
#define FNCHUNK 16
#define JT_PER_CHUNK 32

__global__ __launch_bounds__(256) void k_prev2(const float* __restrict__ prev,
                                               float* __restrict__ prev2,
                                               int nprev) {
    const int wave = threadIdx.x >> 6;
    const int lane = threadIdx.x & 63;
    const int row = blockIdx.x * 4 + wave;
    if (row >= nprev) return;
    const float2 v = *reinterpret_cast<const float2*>(prev + (size_t)row * DIM + 2 * lane);
    float s = v.x * v.x + v.y * v.y;
    #pragma unroll
    for (int m = 1; m < 64; m <<= 1) s += __shfl_xor(s, m);
    if (lane == 0) prev2[row] = s;
}

__global__ __launch_bounds__(256, 1) void k_argmin_fb(
    const float* __restrict__ tg, const float* __restrict__ prev,
    const float* __restrict__ prev2, float2* __restrict__ partial)
{
    __shared__ float4 tgL[TM * 32];
    __shared__ float4 pvL[TN * 32];
    __shared__ float  p2L[TN];
    const int t = threadIdx.x;
    const int rowTile = blockIdx.x;
    const int chunk = blockIdx.y;
    const float4* tgG = reinterpret_cast<const float4*>(tg + (size_t)rowTile * TM * DIM);
    #pragma unroll
    for (int i = 0; i < 16; ++i) {
        const int idx = t + 256 * i;
        const int row = idx >> 5, kk = idx & 31;
        tgL[row * 32 + (kk ^ (row & 7))] = tgG[idx];
    }
    const int tx = t & 15, ty = t >> 4;
    const int sa = ty & 7, sb = tx & 7;
    float minval[8]; int minidx[8];
    #pragma unroll
    for (int ri = 0; ri < 8; ++ri) { minval[ri] = INFINITY; minidx[ri] = 0x7fffffff; }
    const int jchunk0 = chunk * (JT_PER_CHUNK * TN);
    for (int jt = 0; jt < JT_PER_CHUNK; ++jt) {
        const int j0 = jchunk0 + jt * TN;
        __syncthreads();
        const float4* pvG = reinterpret_cast<const float4*>(prev + (size_t)j0 * DIM);
        #pragma unroll
        for (int i = 0; i < 16; ++i) {
            const int idx = t + 256 * i;
            const int row = idx >> 5, kk = idx & 31;
            pvL[row * 32 + (kk ^ (row & 7))] = pvG[idx];
        }
        if (t < TN) p2L[t] = prev2[j0 + t];
        __syncthreads();
        float acc[8][8];
        #pragma unroll
        for (int ri = 0; ri < 8; ++ri)
            #pragma unroll
            for (int ci = 0; ci < 8; ++ci) acc[ri][ci] = 0.f;
        #pragma unroll 2
        for (int kk = 0; kk < 32; ++kk) {
            float4 a[8], b[8];
            const int ka = kk ^ sa, kb = kk ^ sb;
            #pragma unroll
            for (int ri = 0; ri < 8; ++ri) a[ri] = tgL[(ty + 16 * ri) * 32 + ka];
            #pragma unroll
            for (int ci = 0; ci < 8; ++ci) b[ci] = pvL[(tx + 16 * ci) * 32 + kb];
            #pragma unroll
            for (int ri = 0; ri < 8; ++ri)
                #pragma unroll
                for (int ci = 0; ci < 8; ++ci) {
                    acc[ri][ci] += a[ri].x * b[ci].x;
                    acc[ri][ci] += a[ri].y * b[ci].y;
                    acc[ri][ci] += a[ri].z * b[ci].z;
                    acc[ri][ci] += a[ri].w * b[ci].w;
                }
        }
        #pragma unroll
        for (int ci = 0; ci < 8; ++ci) {
            const int jl = tx + 16 * ci;
            const int jg = j0 + jl;
            const float pj = p2L[jl];
            #pragma unroll
            for (int ri = 0; ri < 8; ++ri) {
                const float d = pj - 2.f * acc[ri][ci];
                if (d < minval[ri]) { minval[ri] = d; minidx[ri] = jg; }
            }
        }
    }
    __syncthreads();
    float2* red = reinterpret_cast<float2*>(pvL);
    #pragma unroll
    for (int ri = 0; ri < 8; ++ri) {
        const int row = ty + 16 * ri;
        red[row * 16 + tx] = make_float2(minval[ri], __int_as_float(minidx[ri]));
    }
    __syncthreads();
    if (t < TM) {
        float bv = INFINITY; int bi = 0x7fffffff;
        #pragma unroll
        for (int e = 0; e < 16; ++e) {
            const float2 p = red[t * 16 + e];
            const int pi = __float_as_int(p.y);
            if (p.x < bv || (p.x == bv && pi < bi)) { bv = p.x; bi = pi; }
        }
        partial[(size_t)(rowTile * TM + t) * FNCHUNK + chunk] =
            make_float2(bv, __int_as_float(bi));
    }
}

__global__ __launch_bounds__(256) void k_final_fb(
    const float* __restrict__ tg, const float* __restrict__ rg,
    const float* __restrict__ prev, const float2* __restrict__ partial,
    float* __restrict__ out_vals, float* __restrict__ out_grads)
{
    const int wave = threadIdx.x >> 6, lane = threadIdx.x & 63;
    const int i = blockIdx.x * 4 + wave;
    float bv = INFINITY; int bi = 0x7fffffff;
    if (lane < FNCHUNK) {
        const float2 p = partial[(size_t)i * FNCHUNK + lane];
        bv = p.x; bi = __float_as_int(p.y);
    }
    #pragma unroll
    for (int m = 1; m < 16; m <<= 1) {
        const float ov = __shfl_xor(bv, m);
        const int   oi = __shfl_xor(bi, m);
        if (ov < bv || (ov == bv && oi < bi)) { bv = ov; bi = oi; }
    }
    bi = __shfl(bi, 0);
    const float2 g = *reinterpret_cast<const float2*>(tg   + (size_t)i  * DIM + 2 * lane);
    const float2 s = *reinterpret_cast<const float2*>(prev + (size_t)bi * DIM + 2 * lane);
    const float2 r = *reinterpret_cast<const float2*>(rg   + (size_t)i  * DIM + 2 * lane);
    const float dsx = g.x - s.x, dsy = g.y - s.y;
    const float drx = g.x - r.x, dry = g.y - r.y;
    float ds = dsx * dsx + dsy * dsy;
    float dr = drx * drx + dry * dry;
    #pragma unroll
    for (int m = 1; m < 64; m <<= 1) { ds += __shfl_xor(ds, m); dr += __shfl_xor(dr, m); }
    const float sds = sqrtf(ds), sdr = sqrtf(dr);
    if (lane == 0) out_vals[i] = sds - sdr;
    const float is = 1.0f / sds, ir = 1.0f / sdr;
    float2 gr;
    gr.x = dsx * is - drx * ir;
    gr.y = dsy * is - dry * ir;
    *reinterpret_cast<float2*>(out_grads + (size_t)i * DIM + 2 * lane) = gr;
}

extern "C" void kernel_launch(void* const* d_in, const int* in_sizes, int n_in,
                              void* d_out, int out_size, void* d_ws, size_t ws_size,
                              hipStream_t stream) {
    const float* target  = (const float*)d_in[0];
    const float* reached = (const float*)d_in[1];
    const int n_total = in_sizes[0] / DIM;
    const int nprev = n_total - BATCH;

    const float* tg   = target  + (size_t)nprev * DIM;
    const float* rg   = reached + (size_t)nprev * DIM;
    const float* prev = reached;

    float* out_vals  = (float*)d_out;
    float* out_grads = out_vals + BATCH;

    const size_t offB  = 0;                                 // 16 MiB (16384 frags)
    const size_t offA  = (size_t)16384 * 512 * 2;           // 512 KiB (512 frags)
    const size_t offP2 = offA + (size_t)512 * 512 * 2;      // 256 KiB (p2h)
    const size_t offPP = offP2 + (size_t)NPREV * 4;         // 1 MiB  (p2 partials x4)
    const size_t offPt = offPP + (size_t)NPREV * 4 * 4;     // 2 MiB  (partial top-2)
    const size_t need  = offPt + (size_t)BATCH * NCH * sizeof(float4);

    if (nprev == NPREV && ws_size >= need) {
        u16*    Bb      = (u16*)((char*)d_ws + offB);
        u16*    Ab      = (u16*)((char*)d_ws + offA);
        float*  p2h     = (float*)((char*)d_ws + offP2);
        float*  p2part  = (float*)((char*)d_ws + offPP);
        float4* partial = (float4*)((char*)d_ws + offPt);

        k_conv<<<4224, 256, 0, stream>>>(prev, tg, Bb, Ab, p2part);
        k_prev2r<<<NPREV / 256, 256, 0, stream>>>(p2part, p2h);
        k_gemm_argmin<<<1024, 256, 0, stream>>>(Ab, Bb, p2h, partial);
        k_final2<<<BATCH / 4, 256, 0, stream>>>(tg, rg, prev, partial,
                                                out_vals, out_grads);
    } else {
        float*  prev2   = (float*)d_ws;
        float2* partial = (float2*)((char*)d_ws + (size_t)nprev * sizeof(float));
        k_prev2<<<nprev / 4, 256, 0, stream>>>(prev, prev2, nprev);
        dim3 grid(BATCH / TM, FNCHUNK);
        k_argmin_fb<<<grid, 256, 0, stream>>>(tg, prev, prev2, partial);
        k_final_fb<<<BATCH / 4, 256, 0, stream>>>(tg, rg, prev, partial, out_vals, out_grads);
    }
}

// Round 15
// 60.800 us; speedup vs baseline: 1.1047x; 1.1047x over previous
//
#include <hip/hip_runtime.h>
#include <math.h>

#define DIM 128
#define BATCH 2048
#define NPREV 65536
#define NCH 64          // column chunks (1024 cols each)
#define DELTA 0.8f

typedef __attribute__((ext_vector_type(8))) short bf16x8;
typedef __attribute__((ext_vector_type(4))) float f32x4;
typedef unsigned short u16;

static __device__ __forceinline__ unsigned short f2bf(float f) {
    unsigned int u = __float_as_uint(f);
    u += 0x7FFF + ((u >> 16) & 1);          // RTNE
    return (unsigned short)(u >> 16);
}

// ---------- fused conv: B fragments + fused prev2 partials, and A fragments ----------
// B fragment (chunk,jt,s,fn): 64 lanes x 16B; lane l holds B[col = chunk*1024+jt*64+fn*16+(l&15)]
//   [k = (s>>1)*64 + (s&1)*32 + (l>>4)*8 .. +8].  Linear: frag*512u16 + lane*8.
//   frag = chunk*256 + jt*16 + s*4 + fn.
// p2part[srow*4+s] = sum over that 32-k block (shuffle-reduced over lhi: coalesced, 1MB).
// A fragment (strip,s,fm): 64-row strips; frag = strip*16 + s*4 + fm;
//   lane l holds A[row=strip*64+fm*16+(l&15)], same k mapping.
__global__ __launch_bounds__(256) void k_conv(const float* __restrict__ prevSrc,
                                              const float* __restrict__ tgSrc,
                                              u16* __restrict__ Bdst,
                                              u16* __restrict__ Adst,
                                              float* __restrict__ p2part) {
    const int b = blockIdx.x;
    if (b < 4096) {
        int id = b * 256 + threadIdx.x;           // 16384 frags * 64 lanes
        int lane = id & 63, frag = id >> 6;
        int fn = frag & 3, s = (frag >> 2) & 3, jt = (frag >> 4) & 15, chunk = frag >> 8;
        int srow = chunk * 1024 + jt * 64 + fn * 16 + (lane & 15);
        int scol = (s >> 1) * 64 + (s & 1) * 32 + (lane >> 4) * 8;
        const float* sp = prevSrc + (size_t)srow * DIM + scol;
        float4 f0 = *reinterpret_cast<const float4*>(sp);
        float4 f1 = *reinterpret_cast<const float4*>(sp + 4);
        float f[8] = {f0.x, f0.y, f0.z, f0.w, f1.x, f1.y, f1.z, f1.w};
        union { unsigned short us[8]; uint4 v; } o;
        float sum = 0.f;
        #pragma unroll
        for (int e = 0; e < 8; ++e) { o.us[e] = f2bf(f[e]); sum += f[e] * f[e]; }
        *reinterpret_cast<uint4*>(Bdst + (size_t)id * 8) = o.v;
        sum += __shfl_xor(sum, 16);
        sum += __shfl_xor(sum, 32);
        if ((lane >> 4) == 0) p2part[srow * 4 + s] = sum;   // coalesced-ish, 1 MB total
    } else {
        int id = (b - 4096) * 256 + threadIdx.x;  // 512 frags * 64 lanes
        int lane = id & 63, frag = id >> 6;
        int fm = frag & 3, s = (frag >> 2) & 3, strip = frag >> 4;
        int srow = strip * 64 + fm * 16 + (lane & 15);
        int scol = (s >> 1) * 64 + (s & 1) * 32 + (lane >> 4) * 8;
        const float* sp = tgSrc + (size_t)srow * DIM + scol;
        float4 f0 = *reinterpret_cast<const float4*>(sp);
        float4 f1 = *reinterpret_cast<const float4*>(sp + 4);
        float f[8] = {f0.x, f0.y, f0.z, f0.w, f1.x, f1.y, f1.z, f1.w};
        union { unsigned short us[8]; uint4 v; } o;
        #pragma unroll
        for (int e = 0; e < 8; ++e) o.us[e] = f2bf(f[e]);
        *reinterpret_cast<uint4*>(Adst + (size_t)id * 8) = o.v;
    }
}

// ---------- prev2 reduce: p2h[j] = -0.5 * ||prev_j||^2 (deterministic fixed order) ----------
__global__ __launch_bounds__(256) void k_prev2r(const float* __restrict__ p2part,
                                                float* __restrict__ p2h) {
    int row = blockIdx.x * 256 + threadIdx.x;
    const float4 a = *reinterpret_cast<const float4*>(p2part + (size_t)row * 4);
    p2h[row] = -0.5f * ((a.x + a.y) + (a.z + a.w));
}

// ---------- main: barrier-free, LDS-free all-register GEMM screen (r9/r13-proven) ----------
// grid = 512 blocks x 256 thr = 2048 waves. Wave = 64 rows (strip) x 1024 cols (chunk).
// B fragments streamed global->VGPR (coalesced 1KB loads), double-banked per s-stage.
// Screen s = dot - prev2/2 (maximize). Key stamp: [0:3]=l15 [4:7]=jt; fn group-coded (4).
__global__ __launch_bounds__(256, 2) void k_gemm_argmin(
    const u16* __restrict__ Aimg, const u16* __restrict__ Bimg,
    const float* __restrict__ p2h, float4* __restrict__ partial)
{
    const int t = threadIdx.x;
    const int lane = t & 63;
    const int w = t >> 6;
    const int l15 = lane & 15;
    const int lhi = lane >> 4;

    const int bid = blockIdx.x;
    const int chunk = bid & 63;          // bid%8 == chunk%8 -> XCD-local B stream
    const int strip = (bid >> 6) * 4 + w;

    // A fragments (64 VGPR), persistent
    bf16x8 areg[4][4];
    {
        const u16* ab = Aimg + ((size_t)strip * 16) * 512 + (size_t)lane * 8;
        #pragma unroll
        for (int s = 0; s < 4; ++s)
            #pragma unroll
            for (int fm = 0; fm < 4; ++fm)
                areg[s][fm] = *reinterpret_cast<const bf16x8*>(ab + (s * 4 + fm) * 512);
    }

    const u16* gb = Bimg + ((size_t)chunk * 256) * 512 + (size_t)lane * 8;
    const int phbase = chunk * 1024 + l15;
    const f32x4 z4 = {0.f, 0.f, 0.f, 0.f};

    float v1[4][4], v2[4][4];
    #pragma unroll
    for (int fm = 0; fm < 4; ++fm)
        #pragma unroll
        for (int r = 0; r < 4; ++r) { v1[fm][r] = -INFINITY; v2[fm][r] = -INFINITY; }

    f32x4 acc[4][4];
    bf16x8 bk0[4], bk1[4];

    // prologue: load stage 0 into bank0
    #pragma unroll
    for (int fn = 0; fn < 4; ++fn)
        bk0[fn] = *reinterpret_cast<const bf16x8*>(gb + fn * 512);

#define LOADBANK(BK, G) { \
        const u16* gp_ = gb + (size_t)(G) * 2048; \
        BK[0] = *reinterpret_cast<const bf16x8*>(gp_); \
        BK[1] = *reinterpret_cast<const bf16x8*>(gp_ + 512); \
        BK[2] = *reinterpret_cast<const bf16x8*>(gp_ + 1024); \
        BK[3] = *reinterpret_cast<const bf16x8*>(gp_ + 1536); }

#define MFMA_STAGE_INIT(BK, S) \
        _Pragma("unroll") \
        for (int fm = 0; fm < 4; ++fm) \
            _Pragma("unroll") \
            for (int fn = 0; fn < 4; ++fn) \
                acc[fm][fn] = __builtin_amdgcn_mfma_f32_16x16x32_bf16(areg[S][fm], BK[fn], z4, 0, 0, 0);

#define MFMA_STAGE_ACC(BK, S) \
        _Pragma("unroll") \
        for (int fm = 0; fm < 4; ++fm) \
            _Pragma("unroll") \
            for (int fn = 0; fn < 4; ++fn) \
                acc[fm][fn] = __builtin_amdgcn_mfma_f32_16x16x32_bf16(areg[S][fm], BK[fn], acc[fm][fn], 0, 0, 0);

    for (int jt = 0; jt < 16; ++jt) {
        const int g0 = jt * 4;
        float ph[4];
        #pragma unroll
        for (int fn = 0; fn < 4; ++fn) ph[fn] = p2h[phbase + jt * 64 + fn * 16];

        // s=0: prefetch s=1 into bk1, compute bk0
        LOADBANK(bk1, g0 + 1);
        __builtin_amdgcn_s_setprio(1);
        MFMA_STAGE_INIT(bk0, 0);
        __builtin_amdgcn_s_setprio(0);
        // s=1: prefetch s=2 into bk0, compute bk1
        LOADBANK(bk0, g0 + 2);
        __builtin_amdgcn_s_setprio(1);
        MFMA_STAGE_ACC(bk1, 1);
        __builtin_amdgcn_s_setprio(0);
        // s=2: prefetch s=3 into bk1, compute bk0
        LOADBANK(bk1, g0 + 3);
        __builtin_amdgcn_s_setprio(1);
        MFMA_STAGE_ACC(bk0, 2);
        __builtin_amdgcn_s_setprio(0);
        // s=3: prefetch next jt's s=0 into bk0, compute bk1
        if (jt + 1 < 16) LOADBANK(bk0, g0 + 4);
        __builtin_amdgcn_s_setprio(1);
        MFMA_STAGE_ACC(bk1, 3);
        __builtin_amdgcn_s_setprio(0);

        // epilogue: screen = dot + (-prev2/2); 4-fn max tree, stamped key, top-2
        const unsigned stamp = (unsigned)l15 | ((unsigned)jt << 4);
        #pragma unroll
        for (int fm = 0; fm < 4; ++fm) {
            #pragma unroll
            for (int r = 0; r < 4; ++r) {
                float s0 = acc[fm][0][r] + ph[0];
                float s1 = acc[fm][1][r] + ph[1];
                float s2 = acc[fm][2][r] + ph[2];
                float s3 = acc[fm][3][r] + ph[3];
                float m = fmaxf(fmaxf(s0, s1), fmaxf(s2, s3));
                float key = __uint_as_float((__float_as_uint(m) & ~0x7FFu) | stamp);
                float tm = fminf(v1[fm][r], key);
                v1[fm][r] = fmaxf(v1[fm][r], key);
                v2[fm][r] = fmaxf(v2[fm][r], tm);
            }
        }
    }
#undef LOADBANK
#undef MFMA_STAGE_INIT
#undef MFMA_STAGE_ACC

    // ---- butterfly top-2 merge over the 16 cols (l15) per row; write partial ----
    #pragma unroll
    for (int fm = 0; fm < 4; ++fm) {
        #pragma unroll
        for (int r = 0; r < 4; ++r) {
            float a1 = v1[fm][r], a2 = v2[fm][r];
            #pragma unroll
            for (int m = 1; m < 16; m <<= 1) {
                float o1 = __shfl_xor(a1, m), o2 = __shfl_xor(a2, m);
                float n2 = fmaxf(fminf(a1, o1), fmaxf(a2, o2));
                a1 = fmaxf(a1, o1); a2 = n2;
            }
            if (l15 == 0) {
                unsigned ua = __float_as_uint(a1), ub = __float_as_uint(a2);
                int row = strip * 64 + fm * 16 + lhi * 4 + r;
                int ja = chunk * 1024 + (int)((ua >> 4) & 15) * 64 + (int)(ua & 15);
                int jb = chunk * 1024 + (int)((ub >> 4) & 15) * 64 + (int)(ub & 15);
                partial[(size_t)row * NCH + chunk] = make_float4(
                    -2.0f * __uint_as_float(ua & ~0x7FFu), __int_as_float(ja),
                    -2.0f * __uint_as_float(ub & ~0x7FFu), __int_as_float(jb));
            }
        }
    }
}

// ---------- final: global reduce + exact fp32 recheck (4-col groups) + LP ----------
__global__ __launch_bounds__(256) void k_final2(
    const float* __restrict__ tg, const float* __restrict__ rg,
    const float* __restrict__ prev, const float4* __restrict__ partial,
    float* __restrict__ out_vals, float* __restrict__ out_grads)
{
    const int wv = threadIdx.x >> 6, lane = threadIdx.x & 63;
    const int i = blockIdx.x * 4 + wv;
    const float4 e = partial[(size_t)i * NCH + lane];   // 64 chunks x (top1, top2)

    float bv = e.x;
    #pragma unroll
    for (int m = 1; m < 64; m <<= 1) bv = fminf(bv, __shfl_xor(bv, m));

    unsigned long long m1 = __ballot(e.x <= bv + DELTA);
    unsigned long long m2 = __ballot(e.z <= bv + DELTA);
    const float2 g = *reinterpret_cast<const float2*>(tg + (size_t)i * DIM + 2 * lane);
    const int j1i = __float_as_int(e.y), j2i = __float_as_int(e.w);

    float bestd = INFINITY; int bestj = 0x7fffffff;
    while (m1 | m2) {
        int j0;
        if (m1) { int src = __ffsll(m1) - 1; m1 &= m1 - 1; j0 = __shfl(j1i, src); }
        else    { int src = __ffsll(m2) - 1; m2 &= m2 - 1; j0 = __shfl(j2i, src); }
        #pragma unroll
        for (int f = 0; f < 4; ++f) {
            int cj = j0 + f * 16;
            const float2 p = *reinterpret_cast<const float2*>(prev + (size_t)cj * DIM + 2 * lane);
            float dx = g.x - p.x, dy = g.y - p.y;
            float d = dx * dx + dy * dy;
            #pragma unroll
            for (int m = 1; m < 64; m <<= 1) d += __shfl_xor(d, m);
            if (d < bestd || (d == bestd && cj < bestj)) { bestd = d; bestj = cj; }
        }
    }

    const float2 s = *reinterpret_cast<const float2*>(prev + (size_t)bestj * DIM + 2 * lane);
    const float2 r = *reinterpret_cast<const float2*>(rg + (size_t)i * DIM + 2 * lane);
    const float dsx = g.x - s.x, dsy = g.y - s.y;
    const float drx = g.x - r.x, dry = g.y - r.y;
    float ds = dsx * dsx + dsy * dsy;
    float dr = drx * drx + dry * dry;
    #pragma unroll
    for (int m = 1; m < 64; m <<= 1) { ds += __shfl_xor(ds, m); dr += __shfl_xor(dr, m); }
    const float sds = sqrtf(ds), sdr = sqrtf(dr);
    if (lane == 0) out_vals[i] = sds - sdr;
    const float is = 1.0f / sds, ir = 1.0f / sdr;
    float2 gr;
    gr.x = dsx * is - drx * ir;
    gr.y = dsy * is - dry * ir;
    *reinterpret_cast<float2*>(out_grads + (size_t)i * DIM + 2 * lane) = gr;
}

// ================= fallback (round-1 verified fp32 path) =================
#define TM 128
#define TN 128
#define FNCHUNK 16
#define JT_PER_CHUNK 32

__global__ __launch_bounds__(256) void k_prev2(const float* __restrict__ prev,
                                               float* __restrict__ prev2,
                                               int nprev) {
    const int wave = threadIdx.x >> 6;
    const int lane = threadIdx.x & 63;
    const int row = blockIdx.x * 4 + wave;
    if (row >= nprev) return;
    const float2 v = *reinterpret_cast<const float2*>(prev + (size_t)row * DIM + 2 * lane);
    float s = v.x * v.x + v.y * v.y;
    #pragma unroll
    for (int m = 1; m < 64; m <<= 1) s += __shfl_xor(s, m);
    if (lane == 0) prev2[row] = s;
}

__global__ __launch_bounds__(256, 1) void k_argmin_fb(
    const float* __restrict__ tg, const float* __restrict__ prev,
    const float* __restrict__ prev2, float2* __restrict__ partial)
{
    __shared__ float4 tgL[TM * 32];
    __shared__ float4 pvL[TN * 32];
    __shared__ float  p2L[TN];
    const int t = threadIdx.x;
    const int rowTile = blockIdx.x;
    const int chunk = blockIdx.y;
    const float4* tgG = reinterpret_cast<const float4*>(tg + (size_t)rowTile * TM * DIM);
    #pragma unroll
    for (int i = 0; i < 16; ++i) {
        const int idx = t + 256 * i;
        const int row = idx >> 5, kk = idx & 31;
        tgL[row * 32 + (kk ^ (row & 7))] = tgG[idx];
    }
    const int tx = t & 15, ty = t >> 4;
    const int sa = ty & 7, sb = tx & 7;
    float minval[8]; int minidx[8];
    #pragma unroll
    for (int ri = 0; ri < 8; ++ri) { minval[ri] = INFINITY; minidx[ri] = 0x7fffffff; }
    const int jchunk0 = chunk * (JT_PER_CHUNK * TN);
    for (int jt = 0; jt < JT_PER_CHUNK; ++jt) {
        const int j0 = jchunk0 + jt * TN;
        __syncthreads();
        const float4* pvG = reinterpret_cast<const float4*>(prev + (size_t)j0 * DIM);
        #pragma unroll
        for (int i = 0; i < 16; ++i) {
            const int idx = t + 256 * i;
            const int row = idx >> 5, kk = idx & 31;
            pvL[row * 32 + (kk ^ (row & 7))] = pvG[idx];
        }
        if (t < TN) p2L[t] = prev2[j0 + t];
        __syncthreads();
        float acc[8][8];
        #pragma unroll
        for (int ri = 0; ri < 8; ++ri)
            #pragma unroll
            for (int ci = 0; ci < 8; ++ci) acc[ri][ci] = 0.f;
        #pragma unroll 2
        for (int kk = 0; kk < 32; ++kk) {
            float4 a[8], b[8];
            const int ka = kk ^ sa, kb = kk ^ sb;
            #pragma unroll
            for (int ri = 0; ri < 8; ++ri) a[ri] = tgL[(ty + 16 * ri) * 32 + ka];
            #pragma unroll
            for (int ci = 0; ci < 8; ++ci) b[ci] = pvL[(tx + 16 * ci) * 32 + kb];
            #pragma unroll
            for (int ri = 0; ri < 8; ++ri)
                #pragma unroll
                for (int ci = 0; ci < 8; ++ci) {
                    acc[ri][ci] += a[ri].x * b[ci].x;
                    acc[ri][ci] += a[ri].y * b[ci].y;
                    acc[ri][ci] += a[ri].z * b[ci].z;
                    acc[ri][ci] += a[ri].w * b[ci].w;
                }
        }
        #pragma unroll
        for (int ci = 0; ci < 8; ++ci) {
            const int jl = tx + 16 * ci;
            const int jg = j0 + jl;
            const float pj = p2L[jl];
            #pragma unroll
            for (int ri = 0; ri < 8; ++ri) {
                const float d = pj - 2.f * acc[ri][ci];
                if (d < minval[ri]) { minval[ri] = d; minidx[ri] = jg; }
            }
        }
    }
    __syncthreads();
    float2* red = reinterpret_cast<float2*>(pvL);
    #pragma unroll
    for (int ri = 0; ri < 8; ++ri) {
        const int row = ty + 16 * ri;
        red[row * 16 + tx] = make_float2(minval[ri], __int_as_float(minidx[ri]));
    }
    __syncthreads();
    if (t < TM) {
        float bv = INFINITY; int bi = 0x7fffffff;
        #pragma unroll
        for (int e = 0; e < 16; ++e) {
            const float2 p = red[t * 16 + e];
            const int pi = __float_as_int(p.y);
            if (p.x < bv || (p.x == bv && pi < bi)) { bv = p.x; bi = pi; }
        }
        partial[(size_t)(rowTile * TM + t) * FNCHUNK + chunk] =
            make_float2(bv, __int_as_float(bi));
    }
}

__global__ __launch_bounds__(256) void k_final_fb(
    const float* __restrict__ tg, const float* __restrict__ rg,
    const float* __restrict__ prev, const float2* __restrict__ partial,
    float* __restrict__ out_vals, float* __restrict__ out_grads)
{
    const int wave = threadIdx.x >> 6, lane = threadIdx.x & 63;
    const int i = blockIdx.x * 4 + wave;
    float bv = INFINITY; int bi = 0x7fffffff;
    if (lane < FNCHUNK) {
        const float2 p = partial[(size_t)i * FNCHUNK + lane];
        bv = p.x; bi = __float_as_int(p.y);
    }
    #pragma unroll
    for (int m = 1; m < 16; m <<= 1) {
        const float ov = __shfl_xor(bv, m);
        const int   oi = __shfl_xor(bi, m);
        if (ov < bv || (ov == bv && oi < bi)) { bv = ov; bi = oi; }
    }
    bi = __shfl(bi, 0);
    const float2 g = *reinterpret_cast<const float2*>(tg   + (size_t)i  * DIM + 2 * lane);
    const float2 s = *reinterpret_cast<const float2*>(prev + (size_t)bi * DIM + 2 * lane);
    const float2 r = *reinterpret_cast<const float2*>(rg   + (size_t)i  * DIM + 2 * lane);
    const float dsx = g.x - s.x, dsy = g.y - s.y;
    const float drx = g.x - r.x, dry = g.y - r.y;
    float ds = dsx * dsx + dsy * dsy;
    float dr = drx * drx + dry * dry;
    #pragma unroll
    for (int m = 1; m < 64; m <<= 1) { ds += __shfl_xor(ds, m); dr += __shfl_xor(dr, m); }
    const float sds = sqrtf(ds), sdr = sqrtf(dr);
    if (lane == 0) out_vals[i] = sds - sdr;
    const float is = 1.0f / sds, ir = 1.0f / sdr;
    float2 gr;
    gr.x = dsx * is - drx * ir;
    gr.y = dsy * is - dry * ir;
    *reinterpret_cast<float2*>(out_grads + (size_t)i * DIM + 2 * lane) = gr;
}

extern "C" void kernel_launch(void* const* d_in, const int* in_sizes, int n_in,
                              void* d_out, int out_size, void* d_ws, size_t ws_size,
                              hipStream_t stream) {
    const float* target  = (const float*)d_in[0];
    const float* reached = (const float*)d_in[1];
    const int n_total = in_sizes[0] / DIM;
    const int nprev = n_total - BATCH;

    const float* tg   = target  + (size_t)nprev * DIM;
    const float* rg   = reached + (size_t)nprev * DIM;
    const float* prev = reached;

    float* out_vals  = (float*)d_out;
    float* out_grads = out_vals + BATCH;

    const size_t offB  = 0;                                 // 16 MiB (16384 frags)
    const size_t offA  = (size_t)16384 * 512 * 2;           // 512 KiB (512 frags)
    const size_t offP2 = offA + (size_t)512 * 512 * 2;      // 256 KiB (p2h)
    const size_t offPP = offP2 + (size_t)NPREV * 4;         // 1 MiB  (p2 partials x4)
    const size_t offPt = offPP + (size_t)NPREV * 4 * 4;     // 2 MiB  (partial top-2)
    const size_t need  = offPt + (size_t)BATCH * NCH * sizeof(float4);

    if (nprev == NPREV && ws_size >= need) {
        u16*    Bb      = (u16*)((char*)d_ws + offB);
        u16*    Ab      = (u16*)((char*)d_ws + offA);
        float*  p2h     = (float*)((char*)d_ws + offP2);
        float*  p2part  = (float*)((char*)d_ws + offPP);
        float4* partial = (float4*)((char*)d_ws + offPt);

        k_conv<<<4224, 256, 0, stream>>>(prev, tg, Bb, Ab, p2part);
        k_prev2r<<<NPREV / 256, 256, 0, stream>>>(p2part, p2h);
        k_gemm_argmin<<<512, 256, 0, stream>>>(Ab, Bb, p2h, partial);
        k_final2<<<BATCH / 4, 256, 0, stream>>>(tg, rg, prev, partial,
                                                out_vals, out_grads);
    } else {
        float*  prev2   = (float*)d_ws;
        float2* partial = (float2*)((char*)d_ws + (size_t)nprev * sizeof(float));
        k_prev2<<<nprev / 4, 256, 0, stream>>>(prev, prev2, nprev);
        dim3 grid(BATCH / TM, FNCHUNK);
        k_argmin_fb<<<grid, 256, 0, stream>>>(tg, prev, prev2, partial);
        k_final_fb<<<BATCH / 4, 256, 0, stream>>>(tg, rg, prev, partial, out_vals, out_grads);
    }
}

// Round 16
// 60.017 us; speedup vs baseline: 1.1191x; 1.0131x over previous
//
#include <hip/hip_runtime.h>
#include <math.h>

#define DIM 128
#define BATCH 2048
#define NPREV 65536
#define NCH 64          // column chunks (1024 cols each)
#define DELTA 0.8f

typedef __attribute__((ext_vector_type(8))) short bf16x8;
typedef __attribute__((ext_vector_type(4))) float f32x4;
typedef unsigned short u16;

static __device__ __forceinline__ unsigned short f2bf(float f) {
    unsigned int u = __float_as_uint(f);
    u += 0x7FFF + ((u >> 16) & 1);          // RTNE
    return (unsigned short)(u >> 16);
}

// ---------- fused conv: B fragments + fused prev2 partials, and A fragments ----------
// B fragment (chunk,jt,s,fn): 64 lanes x 16B; lane l holds B[col = chunk*1024+jt*64+fn*16+(l&15)]
//   [k = (s>>1)*64 + (s&1)*32 + (l>>4)*8 .. +8].  Linear: frag*512u16 + lane*8.
//   frag = chunk*256 + jt*16 + s*4 + fn.
// p2part[srow*4+s] = sum over that 32-k block (shuffle-reduced over lhi: coalesced, 1MB).
// A fragment (strip,s,fm): 64-row strips; frag = strip*16 + s*4 + fm;
//   lane l holds A[row=strip*64+fm*16+(l&15)], same k mapping.
__global__ __launch_bounds__(256) void k_conv(const float* __restrict__ prevSrc,
                                              const float* __restrict__ tgSrc,
                                              u16* __restrict__ Bdst,
                                              u16* __restrict__ Adst,
                                              float* __restrict__ p2part) {
    const int b = blockIdx.x;
    if (b < 4096) {
        int id = b * 256 + threadIdx.x;           // 16384 frags * 64 lanes
        int lane = id & 63, frag = id >> 6;
        int fn = frag & 3, s = (frag >> 2) & 3, jt = (frag >> 4) & 15, chunk = frag >> 8;
        int srow = chunk * 1024 + jt * 64 + fn * 16 + (lane & 15);
        int scol = (s >> 1) * 64 + (s & 1) * 32 + (lane >> 4) * 8;
        const float* sp = prevSrc + (size_t)srow * DIM + scol;
        float4 f0 = *reinterpret_cast<const float4*>(sp);
        float4 f1 = *reinterpret_cast<const float4*>(sp + 4);
        float f[8] = {f0.x, f0.y, f0.z, f0.w, f1.x, f1.y, f1.z, f1.w};
        union { unsigned short us[8]; uint4 v; } o;
        float sum = 0.f;
        #pragma unroll
        for (int e = 0; e < 8; ++e) { o.us[e] = f2bf(f[e]); sum += f[e] * f[e]; }
        *reinterpret_cast<uint4*>(Bdst + (size_t)id * 8) = o.v;
        sum += __shfl_xor(sum, 16);
        sum += __shfl_xor(sum, 32);
        if ((lane >> 4) == 0) p2part[srow * 4 + s] = sum;   // coalesced-ish, 1 MB total
    } else {
        int id = (b - 4096) * 256 + threadIdx.x;  // 512 frags * 64 lanes
        int lane = id & 63, frag = id >> 6;
        int fm = frag & 3, s = (frag >> 2) & 3, strip = frag >> 4;
        int srow = strip * 64 + fm * 16 + (lane & 15);
        int scol = (s >> 1) * 64 + (s & 1) * 32 + (lane >> 4) * 8;
        const float* sp = tgSrc + (size_t)srow * DIM + scol;
        float4 f0 = *reinterpret_cast<const float4*>(sp);
        float4 f1 = *reinterpret_cast<const float4*>(sp + 4);
        float f[8] = {f0.x, f0.y, f0.z, f0.w, f1.x, f1.y, f1.z, f1.w};
        union { unsigned short us[8]; uint4 v; } o;
        #pragma unroll
        for (int e = 0; e < 8; ++e) o.us[e] = f2bf(f[e]);
        *reinterpret_cast<uint4*>(Adst + (size_t)id * 8) = o.v;
    }
}

// ---------- prev2 reduce: p2h[j] = -0.5 * ||prev_j||^2 (deterministic fixed order) ----------
__global__ __launch_bounds__(256) void k_prev2r(const float* __restrict__ p2part,
                                                float* __restrict__ p2h) {
    int row = blockIdx.x * 256 + threadIdx.x;
    const float4 a = *reinterpret_cast<const float4*>(p2part + (size_t)row * 4);
    p2h[row] = -0.5f * ((a.x + a.y) + (a.z + a.w));
}

// ---------- main: barrier-free, LDS-free all-register GEMM screen ----------
// grid = 512 blocks x 256 thr = 2048 waves. Wave = 64 rows (strip) x 1024 cols (chunk).
// B fragments streamed global->VGPR (coalesced 1KB loads), double-banked per s-stage.
// Screen value computed via MFMA C-init = -prev2/2 (no epilogue adds); ph double-buffered.
// Key stamp: [0:3]=l15 [4:7]=jt; fn group-coded (4 cols expanded at exact recheck).
__global__ __launch_bounds__(256, 2) void k_gemm_argmin(
    const u16* __restrict__ Aimg, const u16* __restrict__ Bimg,
    const float* __restrict__ p2h, float4* __restrict__ partial)
{
    const int t = threadIdx.x;
    const int lane = t & 63;
    const int w = t >> 6;
    const int l15 = lane & 15;
    const int lhi = lane >> 4;

    const int bid = blockIdx.x;
    const int chunk = bid & 63;          // bid%8 == chunk%8 -> XCD-local B stream
    const int strip = (bid >> 6) * 4 + w;

    // A fragments (64 VGPR), persistent
    bf16x8 areg[4][4];
    {
        const u16* ab = Aimg + ((size_t)strip * 16) * 512 + (size_t)lane * 8;
        #pragma unroll
        for (int s = 0; s < 4; ++s)
            #pragma unroll
            for (int fm = 0; fm < 4; ++fm)
                areg[s][fm] = *reinterpret_cast<const bf16x8*>(ab + (s * 4 + fm) * 512);
    }

    const u16* gb = Bimg + ((size_t)chunk * 256) * 512 + (size_t)lane * 8;
    const int phbase = chunk * 1024 + l15;

    float v1[4][4], v2[4][4];
    #pragma unroll
    for (int fm = 0; fm < 4; ++fm)
        #pragma unroll
        for (int r = 0; r < 4; ++r) { v1[fm][r] = -INFINITY; v2[fm][r] = -INFINITY; }

    f32x4 acc[4][4];
    bf16x8 bk0[4], bk1[4];

    // prologue: load stage 0 into bank0; preload jt=0 ph
    #pragma unroll
    for (int fn = 0; fn < 4; ++fn)
        bk0[fn] = *reinterpret_cast<const bf16x8*>(gb + fn * 512);
    float phc[4];
    #pragma unroll
    for (int fn = 0; fn < 4; ++fn) phc[fn] = p2h[phbase + fn * 16];

#define LOADBANK(BK, G) { \
        const u16* gp_ = gb + (size_t)(G) * 2048; \
        BK[0] = *reinterpret_cast<const bf16x8*>(gp_); \
        BK[1] = *reinterpret_cast<const bf16x8*>(gp_ + 512); \
        BK[2] = *reinterpret_cast<const bf16x8*>(gp_ + 1024); \
        BK[3] = *reinterpret_cast<const bf16x8*>(gp_ + 1536); }

#define MFMA_STAGE_INIT(BK, S) \
        _Pragma("unroll") \
        for (int fm = 0; fm < 4; ++fm) \
            _Pragma("unroll") \
            for (int fn = 0; fn < 4; ++fn) \
                acc[fm][fn] = __builtin_amdgcn_mfma_f32_16x16x32_bf16(areg[S][fm], BK[fn], cin[fn], 0, 0, 0);

#define MFMA_STAGE_ACC(BK, S) \
        _Pragma("unroll") \
        for (int fm = 0; fm < 4; ++fm) \
            _Pragma("unroll") \
            for (int fn = 0; fn < 4; ++fn) \
                acc[fm][fn] = __builtin_amdgcn_mfma_f32_16x16x32_bf16(areg[S][fm], BK[fn], acc[fm][fn], 0, 0, 0);

    for (int jt = 0; jt < 16; ++jt) {
        const int g0 = jt * 4;
        // prefetch next jt's ph (hides p2h latency behind this jt's MFMA block)
        float phn[4];
        if (jt + 1 < 16) {
            #pragma unroll
            for (int fn = 0; fn < 4; ++fn) phn[fn] = p2h[phbase + (jt + 1) * 64 + fn * 16];
        }
        // C-init vectors: screen = dot + (-prev2/2) computed by the matrix pipe
        f32x4 cin[4];
        #pragma unroll
        for (int fn = 0; fn < 4; ++fn)
            cin[fn] = (f32x4){phc[fn], phc[fn], phc[fn], phc[fn]};

        // s=0: prefetch s=1 into bk1, compute bk0
        LOADBANK(bk1, g0 + 1);
        __builtin_amdgcn_s_setprio(1);
        MFMA_STAGE_INIT(bk0, 0);
        __builtin_amdgcn_s_setprio(0);
        // s=1: prefetch s=2 into bk0, compute bk1
        LOADBANK(bk0, g0 + 2);
        __builtin_amdgcn_s_setprio(1);
        MFMA_STAGE_ACC(bk1, 1);
        __builtin_amdgcn_s_setprio(0);
        // s=2: prefetch s=3 into bk1, compute bk0
        LOADBANK(bk1, g0 + 3);
        __builtin_amdgcn_s_setprio(1);
        MFMA_STAGE_ACC(bk0, 2);
        __builtin_amdgcn_s_setprio(0);
        // s=3: prefetch next jt's s=0 into bk0, compute bk1
        if (jt + 1 < 16) LOADBANK(bk0, g0 + 4);
        __builtin_amdgcn_s_setprio(1);
        MFMA_STAGE_ACC(bk1, 3);
        __builtin_amdgcn_s_setprio(0);

        // epilogue: acc IS the screen; 4-fn max tree (max3-friendly), stamped key, top-2
        const unsigned stamp = (unsigned)l15 | ((unsigned)jt << 4);
        #pragma unroll
        for (int fm = 0; fm < 4; ++fm) {
            #pragma unroll
            for (int r = 0; r < 4; ++r) {
                float m = fmaxf(fmaxf(fmaxf(acc[fm][0][r], acc[fm][1][r]),
                                      acc[fm][2][r]), acc[fm][3][r]);
                float key = __uint_as_float((__float_as_uint(m) & ~0x7FFu) | stamp);
                float tm = fminf(v1[fm][r], key);
                v1[fm][r] = fmaxf(v1[fm][r], key);
                v2[fm][r] = fmaxf(v2[fm][r], tm);
            }
        }

        if (jt + 1 < 16) {
            #pragma unroll
            for (int fn = 0; fn < 4; ++fn) phc[fn] = phn[fn];
        }
    }
#undef LOADBANK
#undef MFMA_STAGE_INIT
#undef MFMA_STAGE_ACC

    // ---- butterfly top-2 merge over the 16 cols (l15) per row; write partial ----
    #pragma unroll
    for (int fm = 0; fm < 4; ++fm) {
        #pragma unroll
        for (int r = 0; r < 4; ++r) {
            float a1 = v1[fm][r], a2 = v2[fm][r];
            #pragma unroll
            for (int m = 1; m < 16; m <<= 1) {
                float o1 = __shfl_xor(a1, m), o2 = __shfl_xor(a2, m);
                float n2 = fmaxf(fminf(a1, o1), fmaxf(a2, o2));
                a1 = fmaxf(a1, o1); a2 = n2;
            }
            if (l15 == 0) {
                unsigned ua = __float_as_uint(a1), ub = __float_as_uint(a2);
                int row = strip * 64 + fm * 16 + lhi * 4 + r;
                int ja = chunk * 1024 + (int)((ua >> 4) & 15) * 64 + (int)(ua & 15);
                int jb = chunk * 1024 + (int)((ub >> 4) & 15) * 64 + (int)(ub & 15);
                partial[(size_t)row * NCH + chunk] = make_float4(
                    -2.0f * __uint_as_float(ua & ~0x7FFu), __int_as_float(ja),
                    -2.0f * __uint_as_float(ub & ~0x7FFu), __int_as_float(jb));
            }
        }
    }
}

// ---------- final: global reduce + exact fp32 recheck (4-col groups) + LP ----------
__global__ __launch_bounds__(256) void k_final2(
    const float* __restrict__ tg, const float* __restrict__ rg,
    const float* __restrict__ prev, const float4* __restrict__ partial,
    float* __restrict__ out_vals, float* __restrict__ out_grads)
{
    const int wv = threadIdx.x >> 6, lane = threadIdx.x & 63;
    const int i = blockIdx.x * 4 + wv;
    const float4 e = partial[(size_t)i * NCH + lane];   // 64 chunks x (top1, top2)

    float bv = e.x;
    #pragma unroll
    for (int m = 1; m < 64; m <<= 1) bv = fminf(bv, __shfl_xor(bv, m));

    unsigned long long m1 = __ballot(e.x <= bv + DELTA);
    unsigned long long m2 = __ballot(e.z <= bv + DELTA);
    const float2 g = *reinterpret_cast<const float2*>(tg + (size_t)i * DIM + 2 * lane);
    const int j1i = __float_as_int(e.y), j2i = __float_as_int(e.w);

    float bestd = INFINITY; int bestj = 0x7fffffff;
    while (m1 | m2) {
        int j0;
        if (m1) { int src = __ffsll(m1) - 1; m1 &= m1 - 1; j0 = __shfl(j1i, src); }
        else    { int src = __ffsll(m2) - 1; m2 &= m2 - 1; j0 = __shfl(j2i, src); }
        #pragma unroll
        for (int f = 0; f < 4; ++f) {
            int cj = j0 + f * 16;
            const float2 p = *reinterpret_cast<const float2*>(prev + (size_t)cj * DIM + 2 * lane);
            float dx = g.x - p.x, dy = g.y - p.y;
            float d = dx * dx + dy * dy;
            #pragma unroll
            for (int m = 1; m < 64; m <<= 1) d += __shfl_xor(d, m);
            if (d < bestd || (d == bestd && cj < bestj)) { bestd = d; bestj = cj; }
        }
    }

    const float2 s = *reinterpret_cast<const float2*>(prev + (size_t)bestj * DIM + 2 * lane);
    const float2 r = *reinterpret_cast<const float2*>(rg + (size_t)i * DIM + 2 * lane);
    const float dsx = g.x - s.x, dsy = g.y - s.y;
    const float drx = g.x - r.x, dry = g.y - r.y;
    float ds = dsx * dsx + dsy * dsy;
    float dr = drx * drx + dry * dry;
    #pragma unroll
    for (int m = 1; m < 64; m <<= 1) { ds += __shfl_xor(ds, m); dr += __shfl_xor(dr, m); }
    const float sds = sqrtf(ds), sdr = sqrtf(dr);
    if (lane == 0) out_vals[i] = sds - sdr;
    const float is = 1.0f / sds, ir = 1.0f / sdr;
    float2 gr;
    gr.x = dsx * is - drx * ir;
    gr.y = dsy * is - dry * ir;
    *reinterpret_cast<float2*>(out_grads + (size_t)i * DIM + 2 * lane) = gr;
}

// ================= fallback (round-1 verified fp32 path) =================
#define TM 128
#define TN 128
#define FNCHUNK 16
#define JT_PER_CHUNK 32

__global__ __launch_bounds__(256) void k_prev2(const float* __restrict__ prev,
                                               float* __restrict__ prev2,
                                               int nprev) {
    const int wave = threadIdx.x >> 6;
    const int lane = threadIdx.x & 63;
    const int row = blockIdx.x * 4 + wave;
    if (row >= nprev) return;
    const float2 v = *reinterpret_cast<const float2*>(prev + (size_t)row * DIM + 2 * lane);
    float s = v.x * v.x + v.y * v.y;
    #pragma unroll
    for (int m = 1; m < 64; m <<= 1) s += __shfl_xor(s, m);
    if (lane == 0) prev2[row] = s;
}

__global__ __launch_bounds__(256, 1) void k_argmin_fb(
    const float* __restrict__ tg, const float* __restrict__ prev,
    const float* __restrict__ prev2, float2* __restrict__ partial)
{
    __shared__ float4 tgL[TM * 32];
    __shared__ float4 pvL[TN * 32];
    __shared__ float  p2L[TN];
    const int t = threadIdx.x;
    const int rowTile = blockIdx.x;
    const int chunk = blockIdx.y;
    const float4* tgG = reinterpret_cast<const float4*>(tg + (size_t)rowTile * TM * DIM);
    #pragma unroll
    for (int i = 0; i < 16; ++i) {
        const int idx = t + 256 * i;
        const int row = idx >> 5, kk = idx & 31;
        tgL[row * 32 + (kk ^ (row & 7))] = tgG[idx];
    }
    const int tx = t & 15, ty = t >> 4;
    const int sa = ty & 7, sb = tx & 7;
    float minval[8]; int minidx[8];
    #pragma unroll
    for (int ri = 0; ri < 8; ++ri) { minval[ri] = INFINITY; minidx[ri] = 0x7fffffff; }
    const int jchunk0 = chunk * (JT_PER_CHUNK * TN);
    for (int jt = 0; jt < JT_PER_CHUNK; ++jt) {
        const int j0 = jchunk0 + jt * TN;
        __syncthreads();
        const float4* pvG = reinterpret_cast<const float4*>(prev + (size_t)j0 * DIM);
        #pragma unroll
        for (int i = 0; i < 16; ++i) {
            const int idx = t + 256 * i;
            const int row = idx >> 5, kk = idx & 31;
            pvL[row * 32 + (kk ^ (row & 7))] = pvG[idx];
        }
        if (t < TN) p2L[t] = prev2[j0 + t];
        __syncthreads();
        float acc[8][8];
        #pragma unroll
        for (int ri = 0; ri < 8; ++ri)
            #pragma unroll
            for (int ci = 0; ci < 8; ++ci) acc[ri][ci] = 0.f;
        #pragma unroll 2
        for (int kk = 0; kk < 32; ++kk) {
            float4 a[8], b[8];
            const int ka = kk ^ sa, kb = kk ^ sb;
            #pragma unroll
            for (int ri = 0; ri < 8; ++ri) a[ri] = tgL[(ty + 16 * ri) * 32 + ka];
            #pragma unroll
            for (int ci = 0; ci < 8; ++ci) b[ci] = pvL[(tx + 16 * ci) * 32 + kb];
            #pragma unroll
            for (int ri = 0; ri < 8; ++ri)
                #pragma unroll
                for (int ci = 0; ci < 8; ++ci) {
                    acc[ri][ci] += a[ri].x * b[ci].x;
                    acc[ri][ci] += a[ri].y * b[ci].y;
                    acc[ri][ci] += a[ri].z * b[ci].z;
                    acc[ri][ci] += a[ri].w * b[ci].w;
                }
        }
        #pragma unroll
        for (int ci = 0; ci < 8; ++ci) {
            const int jl = tx + 16 * ci;
            const int jg = j0 + jl;
            const float pj = p2L[jl];
            #pragma unroll
            for (int ri = 0; ri < 8; ++ri) {
                const float d = pj - 2.f * acc[ri][ci];
                if (d < minval[ri]) { minval[ri] = d; minidx[ri] = jg; }
            }
        }
    }
    __syncthreads();
    float2* red = reinterpret_cast<float2*>(pvL);
    #pragma unroll
    for (int ri = 0; ri < 8; ++ri) {
        const int row = ty + 16 * ri;
        red[row * 16 + tx] = make_float2(minval[ri], __int_as_float(minidx[ri]));
    }
    __syncthreads();
    if (t < TM) {
        float bv = INFINITY; int bi = 0x7fffffff;
        #pragma unroll
        for (int e = 0; e < 16; ++e) {
            const float2 p = red[t * 16 + e];
            const int pi = __float_as_int(p.y);
            if (p.x < bv || (p.x == bv && pi < bi)) { bv = p.x; bi = pi; }
        }
        partial[(size_t)(rowTile * TM + t) * FNCHUNK + chunk] =
            make_float2(bv, __int_as_float(bi));
    }
}

__global__ __launch_bounds__(256) void k_final_fb(
    const float* __restrict__ tg, const float* __restrict__ rg,
    const float* __restrict__ prev, const float2* __restrict__ partial,
    float* __restrict__ out_vals, float* __restrict__ out_grads)
{
    const int wave = threadIdx.x >> 6, lane = threadIdx.x & 63;
    const int i = blockIdx.x * 4 + wave;
    float bv = INFINITY; int bi = 0x7fffffff;
    if (lane < FNCHUNK) {
        const float2 p = partial[(size_t)i * FNCHUNK + lane];
        bv = p.x; bi = __float_as_int(p.y);
    }
    #pragma unroll
    for (int m = 1; m < 16; m <<= 1) {
        const float ov = __shfl_xor(bv, m);
        const int   oi = __shfl_xor(bi, m);
        if (ov < bv || (ov == bv && oi < bi)) { bv = ov; bi = oi; }
    }
    bi = __shfl(bi, 0);
    const float2 g = *reinterpret_cast<const float2*>(tg   + (size_t)i  * DIM + 2 * lane);
    const float2 s = *reinterpret_cast<const float2*>(prev + (size_t)bi * DIM + 2 * lane);
    const float2 r = *reinterpret_cast<const float2*>(rg   + (size_t)i  * DIM + 2 * lane);
    const float dsx = g.x - s.x, dsy = g.y - s.y;
    const float drx = g.x - r.x, dry = g.y - r.y;
    float ds = dsx * dsx + dsy * dsy;
    float dr = drx * drx + dry * dry;
    #pragma unroll
    for (int m = 1; m < 64; m <<= 1) { ds += __shfl_xor(ds, m); dr += __shfl_xor(dr, m); }
    const float sds = sqrtf(ds), sdr = sqrtf(dr);
    if (lane == 0) out_vals[i] = sds - sdr;
    const float is = 1.0f / sds, ir = 1.0f / sdr;
    float2 gr;
    gr.x = dsx * is - drx * ir;
    gr.y = dsy * is - dry * ir;
    *reinterpret_cast<float2*>(out_grads + (size_t)i * DIM + 2 * lane) = gr;
}

extern "C" void kernel_launch(void* const* d_in, const int* in_sizes, int n_in,
                              void* d_out, int out_size, void* d_ws, size_t ws_size,
                              hipStream_t stream) {
    const float* target  = (const float*)d_in[0];
    const float* reached = (const float*)d_in[1];
    const int n_total = in_sizes[0] / DIM;
    const int nprev = n_total - BATCH;

    const float* tg   = target  + (size_t)nprev * DIM;
    const float* rg   = reached + (size_t)nprev * DIM;
    const float* prev = reached;

    float* out_vals  = (float*)d_out;
    float* out_grads = out_vals + BATCH;

    const size_t offB  = 0;                                 // 16 MiB (16384 frags)
    const size_t offA  = (size_t)16384 * 512 * 2;           // 512 KiB (512 frags)
    const size_t offP2 = offA + (size_t)512 * 512 * 2;      // 256 KiB (p2h)
    const size_t offPP = offP2 + (size_t)NPREV * 4;         // 1 MiB  (p2 partials x4)
    const size_t offPt = offPP + (size_t)NPREV * 4 * 4;     // 2 MiB  (partial top-2)
    const size_t need  = offPt + (size_t)BATCH * NCH * sizeof(float4);

    if (nprev == NPREV && ws_size >= need) {
        u16*    Bb      = (u16*)((char*)d_ws + offB);
        u16*    Ab      = (u16*)((char*)d_ws + offA);
        float*  p2h     = (float*)((char*)d_ws + offP2);
        float*  p2part  = (float*)((char*)d_ws + offPP);
        float4* partial = (float4*)((char*)d_ws + offPt);

        k_conv<<<4224, 256, 0, stream>>>(prev, tg, Bb, Ab, p2part);
        k_prev2r<<<NPREV / 256, 256, 0, stream>>>(p2part, p2h);
        k_gemm_argmin<<<512, 256, 0, stream>>>(Ab, Bb, p2h, partial);
        k_final2<<<BATCH / 4, 256, 0, stream>>>(tg, rg, prev, partial,
                                                out_vals, out_grads);
    } else {
        float*  prev2   = (float*)d_ws;
        float2* partial = (float2*)((char*)d_ws + (size_t)nprev * sizeof(float));
        k_prev2<<<nprev / 4, 256, 0, stream>>>(prev, prev2, nprev);
        dim3 grid(BATCH / TM, FNCHUNK);
        k_argmin_fb<<<grid, 256, 0, stream>>>(tg, prev, prev2, partial);
        k_final_fb<<<BATCH / 4, 256, 0, stream>>>(tg, rg, prev, partial, out_vals, out_grads);
    }
}